// Round 2
// baseline (227.094 us; speedup 1.0000x reference)
//
#include <hip/hip_runtime.h>

typedef __bf16 bf16;
typedef __attribute__((ext_vector_type(8))) __bf16 bf16x8;
typedef __attribute__((ext_vector_type(4))) __bf16 bf16x4;
typedef __attribute__((ext_vector_type(4))) float f32x4;

__device__ __forceinline__ void gload16(const void* g, void* l) {
  __builtin_amdgcn_global_load_lds(
      (__attribute__((address_space(1))) void*)(g),
      (__attribute__((address_space(3))) void*)(l), 16, 0, 0);
}

// ---------------------------------------------------------------------------
// Workspace layout (bytes):
//   xh  : NHWC padded input, bf16 [130][130][512]        = 17,305,600
//   w1t : conv1 weights,     bf16 [9][512 oc][512 c]     =  4,718,592
//   w2p : packed head wts,   bf16 [80 oc2][512 c]        =     81,920
//   mid : conv1 output NHWC, bf16 [16384 px][512 oc]     = 16,777,216
// ---------------------------------------------------------------------------
#define WS_XH   0
#define WS_W1T  17305600
#define WS_W2P  22024192
#define WS_MID  22106112

#define OUT_CLS 786432
#define OUT_ROI 1179648

// ---------------- prep: zero only the halo border of xh --------------------
// xh as int4: pixel = 64 int4, padded row = 130*64 = 8320 int4.
// blocks 0..129: row b, cols 0 & 129. blocks 130/131: full rows 0 / 129.
__global__ void zero_border(int4* __restrict__ xh4) {
  const int t = threadIdx.x;
  const int b = blockIdx.x;
  const int4 z = make_int4(0, 0, 0, 0);
  if (b < 130) {
    if (t < 64)       xh4[(b * 130 + 0) * 64 + t] = z;
    else if (t < 128) xh4[(b * 130 + 129) * 64 + (t - 64)] = z;
  } else {
    const int r = (b == 130) ? 0 : 129;
    for (int i = t; i < 8320; i += 256) xh4[r * 8320 + i] = z;
  }
}

// ---------------- prep: NCHW fp32 -> NHWC bf16 interior transpose ----------
__global__ void transpose_x(const float* __restrict__ x, bf16* __restrict__ xh) {
  __shared__ float lds[64][65];
  const int tid  = threadIdx.x;
  const int ct   = blockIdx.x & 7;
  const int colt = (blockIdx.x >> 3) & 1;
  const int r    = 1 + (blockIdx.x >> 4);
  const int c0   = ct * 64;
  const int col0 = 1 + colt * 64;
  const int lcol = tid & 63;
  const int coff = tid >> 6;
#pragma unroll
  for (int i = 0; i < 16; ++i) {
    const int cl = coff + i * 4;
    lds[cl][lcol] = x[(long)(c0 + cl) * 16384 + (r - 1) * 128 + (col0 - 1) + lcol];
  }
  __syncthreads();
#pragma unroll
  for (int i = 0; i < 16; ++i) {
    const int coll = coff + i * 4;
    xh[(long)(r * 130 + col0 + coll) * 512 + c0 + lcol] = (bf16)lds[lcol][coll];
  }
}

// ---------------- prep: conv1_w [oc][c][3][3] fp32 -> w1t [j][oc][c] bf16 --
// Coalesced: block reads 2304 consecutive floats (256 (oc,c) pairs x 9 j),
// LDS-transposes, writes 9 contiguous 512B runs. 1024 blocks.
__global__ void prep_w1(const float* __restrict__ w1, bf16* __restrict__ w1t) {
  __shared__ float lds[2304];
  const int t = threadIdx.x;
  const long base = (long)blockIdx.x * 2304;
#pragma unroll
  for (int i = 0; i < 9; ++i) lds[i * 256 + t] = w1[base + i * 256 + t];
  __syncthreads();
  const int pair0 = blockIdx.x * 256;   // pair = oc*512 + c
#pragma unroll
  for (int j = 0; j < 9; ++j)
    w1t[(long)j * 262144 + pair0 + t] = (bf16)lds[t * 9 + j];
}

// ---------------- prep: pack loc_w(48)+score_w(24)+zeros(8) -> w2p[80][512] -
__global__ void prep_w2(const float* __restrict__ loc_w,
                        const float* __restrict__ score_w,
                        bf16* __restrict__ w2p) {
  const int idx = blockIdx.x * 256 + threadIdx.x;
  const int c  = idx & 511;
  const int oc = idx >> 9;
  float v = 0.f;
  if (oc < 48)      v = loc_w[oc * 512 + c];
  else if (oc < 72) v = score_w[(oc - 48) * 512 + c];
  w2p[idx] = (bf16)v;
}

// ---------------- conv1 implicit GEMM, single-barrier double-buffered ------
// C[oc,px] = sum_{j,c} w1t[j][oc][c] * xh[(h+ky)*130+(w+kx)][c]
// 512 blocks = 4 oc-tiles x 128 px-rows; 128x128 tile; 144 stages of BK=32.
// Stage s+1's global_load_lds issue right after barrier s -> loads in flight
// during stage s's ds_read+MFMA; barrier s+1's vmcnt(0) drains loads that had
// a full stage to complete.
__global__ __launch_bounds__(256, 2) void conv1_gemm(
    const bf16* __restrict__ w1t, const bf16* __restrict__ xh,
    const float* __restrict__ b1, bf16* __restrict__ mid) {
  __shared__ bf16 ldsA[2][128 * 32];
  __shared__ bf16 ldsB[2][128 * 32];
  const int tid  = threadIdx.x;
  const int wave = tid >> 6;
  const int lane = tid & 63;
  const int quad = lane >> 4;
  const int l15  = lane & 15;
  const int wr = wave >> 1, wc = wave & 1;
  const int oc_tile = blockIdx.x & 3;
  const int h       = blockIdx.x >> 2;
  const char* w1tB = (const char*)w1t + (long)oc_tile * 131072;
  const char* xhB  = (const char*)xh;
  const int srow  = lane >> 2;
  const int sbyte = (lane & 3) * 16;

  auto stage = [&](int s, int pb) {
    const int j  = s >> 4, ck = s & 15;
    const int ky = j / 3, kx = j - ky * 3;
    const char* aB = w1tB + (long)j * 524288 + ck * 64;
    const char* bB = xhB + (long)((h + ky) * 130 + kx) * 1024 + ck * 64;
#pragma unroll
    for (int call = 0; call < 2; ++call) {
      const int row = wave * 32 + call * 16;
      gload16(aB + (long)(row + srow) * 1024 + sbyte, (char*)&ldsA[pb][0] + row * 64);
      gload16(bB + (long)(row + srow) * 1024 + sbyte, (char*)&ldsB[pb][0] + row * 64);
    }
  };

  f32x4 acc[4][4];
#pragma unroll
  for (int i = 0; i < 4; ++i)
#pragma unroll
    for (int k = 0; k < 4; ++k) acc[i][k] = (f32x4){0.f, 0.f, 0.f, 0.f};

  stage(0, 0);

  for (int s = 0; s < 144; ++s) {
    const int pb = s & 1;
    __syncthreads();                 // drains stage-s loads; protects buffers
    if (s < 143) stage(s + 1, pb ^ 1);
    bf16x8 af[4], bfr[4];
#pragma unroll
    for (int mi = 0; mi < 4; ++mi)
      af[mi] = *(const bf16x8*)&ldsA[pb][(wr * 64 + mi * 16 + l15) * 32 + quad * 8];
#pragma unroll
    for (int ni = 0; ni < 4; ++ni)
      bfr[ni] = *(const bf16x8*)&ldsB[pb][(wc * 64 + ni * 16 + l15) * 32 + quad * 8];
#pragma unroll
    for (int mi = 0; mi < 4; ++mi)
#pragma unroll
      for (int ni = 0; ni < 4; ++ni)
        acc[mi][ni] = __builtin_amdgcn_mfma_f32_16x16x32_bf16(
            af[mi], bfr[ni], acc[mi][ni], 0, 0, 0);
  }

  // epilogue: bias + relu, store bf16 NHWC mid[px][oc]
#pragma unroll
  for (int mi = 0; mi < 4; ++mi) {
    const int oc = oc_tile * 128 + wr * 64 + mi * 16 + quad * 4;
    const float bv0 = b1[oc], bv1 = b1[oc + 1], bv2 = b1[oc + 2], bv3 = b1[oc + 3];
#pragma unroll
    for (int ni = 0; ni < 4; ++ni) {
      const int px = wc * 64 + ni * 16 + l15;
      f32x4 a = acc[mi][ni];
      float t0 = a[0] + bv0; t0 = t0 > 0.f ? t0 : 0.f;
      float t1 = a[1] + bv1; t1 = t1 > 0.f ? t1 : 0.f;
      float t2 = a[2] + bv2; t2 = t2 > 0.f ? t2 : 0.f;
      float t3 = a[3] + bv3; t3 = t3 > 0.f ? t3 : 0.f;
      bf16x4 v = {(bf16)t0, (bf16)t1, (bf16)t2, (bf16)t3};
      *(bf16x4*)(mid + (long)(h * 128 + px) * 512 + oc) = v;
    }
  }
}

// ---------------- head: barrier-free K-split GEMM + anchor decode ----------
// 1024 blocks x 16 px. 4 waves each take a K-quarter (128 ch, 4 BK=32 steps),
// fragments loaded directly from global (w2p is 80KB -> L2-hot; mid rows are
// 64B-contiguous per lane group). LDS only for the final 4-way reduction.
__global__ __launch_bounds__(256) void head_gemm(
    const bf16* __restrict__ w2p, const bf16* __restrict__ mid,
    const float* __restrict__ loc_b, const float* __restrict__ score_b,
    float* __restrict__ out) {
  __shared__ f32x4 red[3][64][5];
  const int tid  = threadIdx.x;
  const int wave = tid >> 6;
  const int lane = tid & 63;
  const int quad = lane >> 4;
  const int l15  = lane & 15;
  const int px0  = blockIdx.x * 16;
  const bf16* mB = mid + (long)px0 * 512;

  f32x4 acc[5];
#pragma unroll
  for (int i = 0; i < 5; ++i) acc[i] = (f32x4){0.f, 0.f, 0.f, 0.f};

#pragma unroll
  for (int st = 0; st < 4; ++st) {
    const int k0 = wave * 128 + st * 32;
    bf16x8 bfr = *(const bf16x8*)(mB + (long)l15 * 512 + k0 + quad * 8);
#pragma unroll
    for (int mi = 0; mi < 5; ++mi) {
      bf16x8 af = *(const bf16x8*)(w2p + (long)(mi * 16 + l15) * 512 + k0 + quad * 8);
      acc[mi] = __builtin_amdgcn_mfma_f32_16x16x32_bf16(af, bfr, acc[mi], 0, 0, 0);
    }
  }

  if (wave > 0) {
#pragma unroll
    for (int mi = 0; mi < 5; ++mi) red[wave - 1][lane][mi] = acc[mi];
  }
  __syncthreads();
  if (wave != 0) return;
#pragma unroll
  for (int w = 0; w < 3; ++w)
#pragma unroll
    for (int mi = 0; mi < 5; ++mi) acc[mi] += red[w][lane][mi];

  // epilogue: oc2 = mi*16 + quad*4 + r ; px = px0 + l15
  const int p    = px0 + l15;
  const int hh   = p >> 7;
  const int wcol = p & 127;
  const float cx = 16.f * (float)hh;
  const float cy = 16.f * (float)wcol;
  const float s0 = quad == 0 ? 45.f : quad == 1 ? 91.f : quad == 2 ? 181.f : 362.f;
  const float s1 = quad == 0 ? 32.f : quad == 1 ? 64.f : quad == 2 ? 128.f : 256.f;
  const float s2 = quad == 0 ? 23.f : quad == 1 ? 45.f : quad == 2 ? 91.f : 181.f;
  const float aw[3] = {s0, s1, s2};
  const float ah[3] = {s2, s1, s0};
#pragma unroll
  for (int mi = 0; mi < 5; ++mi) {
#pragma unroll
    for (int r = 0; r < 4; ++r) {
      const int oc2 = mi * 16 + quad * 4 + r;
      float v = acc[mi][r];
      if (mi < 3) {
        v += loc_b[oc2];
        out[p * 48 + oc2] = v;
        float roi;
        if (r == 0)      roi = v * aw[mi] + cx;
        else if (r == 1) roi = v * ah[mi] + cy;
        else if (r == 2) roi = __expf(v) * aw[mi];
        else             roi = __expf(v) * ah[mi];
        out[OUT_ROI + p * 48 + oc2] = roi;
      } else {
        const int sc = oc2 - 48;
        if (sc < 24) {
          v += score_b[sc];
          out[OUT_CLS + p * 24 + sc] = v;
        }
      }
    }
  }
}

// ---------------------------------------------------------------------------
extern "C" void kernel_launch(void* const* d_in, const int* in_sizes, int n_in,
                              void* d_out, int out_size, void* d_ws, size_t ws_size,
                              hipStream_t stream) {
  (void)in_sizes; (void)n_in; (void)out_size; (void)ws_size;
  const float* x       = (const float*)d_in[0];
  const float* conv1_w = (const float*)d_in[1];
  const float* conv1_b = (const float*)d_in[2];
  const float* score_w = (const float*)d_in[3];
  const float* score_b = (const float*)d_in[4];
  const float* loc_w   = (const float*)d_in[5];
  const float* loc_b   = (const float*)d_in[6];
  char* ws = (char*)d_ws;
  bf16* xh  = (bf16*)(ws + WS_XH);
  bf16* w1t = (bf16*)(ws + WS_W1T);
  bf16* w2p = (bf16*)(ws + WS_W2P);
  bf16* mid = (bf16*)(ws + WS_MID);
  float* out = (float*)d_out;

  hipLaunchKernelGGL(zero_border, dim3(132),  dim3(256), 0, stream, (int4*)xh);
  hipLaunchKernelGGL(transpose_x, dim3(2048), dim3(256), 0, stream, x, xh);
  hipLaunchKernelGGL(prep_w1,     dim3(1024), dim3(256), 0, stream, conv1_w, w1t);
  hipLaunchKernelGGL(prep_w2,     dim3(160),  dim3(256), 0, stream, loc_w, score_w, w2p);
  hipLaunchKernelGGL(conv1_gemm,  dim3(512),  dim3(256), 0, stream, w1t, xh, conv1_b, mid);
  hipLaunchKernelGGL(head_gemm,   dim3(1024), dim3(256), 0, stream, w2p, mid, loc_b, score_b, out);
}

// Round 3
// 217.337 us; speedup vs baseline: 1.0449x; 1.0449x over previous
//
#include <hip/hip_runtime.h>

typedef __bf16 bf16;
typedef __attribute__((ext_vector_type(8))) __bf16 bf16x8;
typedef __attribute__((ext_vector_type(4))) __bf16 bf16x4;
typedef __attribute__((ext_vector_type(4))) float f32x4;

__device__ __forceinline__ void gload16(const void* g, void* l) {
  __builtin_amdgcn_global_load_lds(
      (__attribute__((address_space(1))) void*)(g),
      (__attribute__((address_space(3))) void*)(l), 16, 0, 0);
}

// ---------------------------------------------------------------------------
// Workspace layout (bytes):
//   xh  : NHWC padded input, bf16 [130][130][512]        = 17,305,600
//   w1t : conv1 weights,     bf16 [9][512 oc][512 c]     =  4,718,592
//   w2p : packed head wts,   bf16 [80 oc2][512 c]        =     81,920
//   mid : conv1 output NHWC, bf16 [16384 px][512 oc]     = 16,777,216
// ---------------------------------------------------------------------------
#define WS_XH   0
#define WS_W1T  17305600
#define WS_W2P  22024192
#define WS_MID  22106112

#define OUT_CLS 786432
#define OUT_ROI 1179648

// ---------------- fused prep: zero border | w1 repack | w2 pack ------------
// grid = 132 (border) + 1024 (w1) + 160 (w2) = 1316 blocks
__global__ void prep_misc(int4* __restrict__ xh4,
                          const float* __restrict__ w1, bf16* __restrict__ w1t,
                          const float* __restrict__ loc_w,
                          const float* __restrict__ score_w,
                          bf16* __restrict__ w2p) {
  __shared__ float lds[2304];
  const int t = threadIdx.x;
  const int b = blockIdx.x;
  if (b < 132) {
    const int4 z = make_int4(0, 0, 0, 0);
    if (b < 130) {
      if (t < 64)       xh4[(b * 130 + 0) * 64 + t] = z;
      else if (t < 128) xh4[(b * 130 + 129) * 64 + (t - 64)] = z;
    } else {
      const int r = (b == 130) ? 0 : 129;
      for (int i = t; i < 8320; i += 256) xh4[r * 8320 + i] = z;
    }
  } else if (b < 132 + 1024) {
    const int bb = b - 132;
    const long base = (long)bb * 2304;
#pragma unroll
    for (int i = 0; i < 9; ++i) lds[i * 256 + t] = w1[base + i * 256 + t];
    __syncthreads();
    const int pair0 = bb * 256;   // pair = oc*512 + c
#pragma unroll
    for (int j = 0; j < 9; ++j)
      w1t[(long)j * 262144 + pair0 + t] = (bf16)lds[t * 9 + j];
  } else {
    const int idx = (b - 1156) * 256 + t;   // 80*512 = 40960
    const int c  = idx & 511;
    const int oc = idx >> 9;
    float v = 0.f;
    if (oc < 48)      v = loc_w[oc * 512 + c];
    else if (oc < 72) v = score_w[(oc - 48) * 512 + c];
    w2p[idx] = (bf16)v;
  }
}

// ---------------- prep: NCHW fp32 -> NHWC bf16 interior transpose ----------
__global__ void transpose_x(const float* __restrict__ x, bf16* __restrict__ xh) {
  __shared__ float lds[64][65];
  const int tid  = threadIdx.x;
  const int ct   = blockIdx.x & 7;
  const int colt = (blockIdx.x >> 3) & 1;
  const int r    = 1 + (blockIdx.x >> 4);
  const int c0   = ct * 64;
  const int col0 = 1 + colt * 64;
  const int lcol = tid & 63;
  const int coff = tid >> 6;
#pragma unroll
  for (int i = 0; i < 16; ++i) {
    const int cl = coff + i * 4;
    lds[cl][lcol] = x[(long)(c0 + cl) * 16384 + (r - 1) * 128 + (col0 - 1) + lcol];
  }
  __syncthreads();
#pragma unroll
  for (int i = 0; i < 16; ++i) {
    const int coll = coff + i * 4;
    xh[(long)(r * 130 + col0 + coll) * 512 + c0 + lcol] = (bf16)lds[lcol][coll];
  }
}

// ---------------- conv1 implicit GEMM, issue-ahead pipeline ----------------
// C[oc,px] = sum_{j,c} w1t[j][oc][c] * xh[(h+ky)*130+(w+kx)][c]
// 512 blocks = 4 oc-tiles x 128 px-rows; 128x128 tile; 144 stages of BK=32.
// Per stage: vmcnt(0) [my prior loads landed] -> bare s_barrier [all waves'
// landed; all readers of the buffer being refilled are done] -> issue next
// stage's global_load_lds -> compute current stage. Prefetch loads stay in
// flight across the whole compute phase; forced drains (if any) land before
// the barrier where outstanding == 0. Static buffer names so the compiler
// can disambiguate gload targets from ds_read sources (no false vmcnt(0)).
// LDS chunk swizzle: phys 16B-chunk = logical ^ ((row>>1)&3) -> fragment
// reads go 8-way -> 2-way banked (free).
// Block swizzle: h = (blk&7)*16 + (blk>>3 & 15): each XCD (blk%8, assumed
// round-robin) streams a private 16-row xh band -> L2 locality.
__global__ __launch_bounds__(256, 2) void conv1_gemm(
    const bf16* __restrict__ w1t, const bf16* __restrict__ xh,
    const float* __restrict__ b1, bf16* __restrict__ mid) {
  __shared__ bf16 A0[4096], B0[4096], A1[4096], B1[4096];   // 8 KB each
  const int tid  = threadIdx.x;
  const int wave = tid >> 6;
  const int lane = tid & 63;
  const int quad = lane >> 4;
  const int l15  = lane & 15;
  const int wr = wave >> 1, wc = wave & 1;
  const int blk     = blockIdx.x;
  const int oc_tile = blk >> 7;
  const int hraw    = blk & 127;
  const int h       = ((hraw & 7) << 4) + (hraw >> 3);
  const char* w1tB = (const char*)w1t + (long)oc_tile * 131072;
  const char* xhB  = (const char*)xh;
  const int srow = lane >> 2;                               // 16 rows/call
  const int ssw  = (((lane & 3) ^ ((lane >> 3) & 3)) << 4); // swizzled src chunk
  const int swq  = (quad ^ ((l15 >> 1) & 3)) << 3;          // swizzled frag elem

  auto stage = [&](int s, bf16* At, bf16* Bt) {
    const int j  = s >> 4, ck = s & 15;
    const int ky = j / 3, kx = j - ky * 3;
    const char* aB = w1tB + (long)j * 524288 + ck * 64;
    const char* bB = xhB + (long)((h + ky) * 130 + kx) * 1024 + ck * 64;
#pragma unroll
    for (int c = 0; c < 2; ++c) {
      const int r0 = wave * 32 + c * 16;
      gload16(aB + (long)(r0 + srow) * 1024 + ssw, (char*)At + r0 * 64);
      gload16(bB + (long)(r0 + srow) * 1024 + ssw, (char*)Bt + r0 * 64);
    }
  };

  f32x4 acc[4][4];
#pragma unroll
  for (int i = 0; i < 4; ++i)
#pragma unroll
    for (int k = 0; k < 4; ++k) acc[i][k] = (f32x4){0.f, 0.f, 0.f, 0.f};

  auto compute = [&](const bf16* A, const bf16* B) {
    bf16x8 af[4], bfr[4];
#pragma unroll
    for (int mi = 0; mi < 4; ++mi)
      af[mi] = *(const bf16x8*)&A[(wr * 64 + mi * 16 + l15) * 32 + swq];
#pragma unroll
    for (int ni = 0; ni < 4; ++ni)
      bfr[ni] = *(const bf16x8*)&B[(wc * 64 + ni * 16 + l15) * 32 + swq];
#pragma unroll
    for (int mi = 0; mi < 4; ++mi)
#pragma unroll
      for (int ni = 0; ni < 4; ++ni)
        acc[mi][ni] = __builtin_amdgcn_mfma_f32_16x16x32_bf16(
            af[mi], bfr[ni], acc[mi][ni], 0, 0, 0);
  };

  stage(0, A0, B0);
  for (int s = 0; s < 144; s += 2) {
    asm volatile("s_waitcnt vmcnt(0)" ::: "memory");
    __builtin_amdgcn_s_barrier();
    stage(s + 1, A1, B1);            // s+1 <= 143 always
    compute(A0, B0);
    asm volatile("s_waitcnt vmcnt(0)" ::: "memory");
    __builtin_amdgcn_s_barrier();
    if (s + 2 < 144) stage(s + 2, A0, B0);
    compute(A1, B1);
  }

  // epilogue: bias + relu, store bf16 NHWC mid[px][oc]
#pragma unroll
  for (int mi = 0; mi < 4; ++mi) {
    const int oc = oc_tile * 128 + wr * 64 + mi * 16 + quad * 4;
    const float bv0 = b1[oc], bv1 = b1[oc + 1], bv2 = b1[oc + 2], bv3 = b1[oc + 3];
#pragma unroll
    for (int ni = 0; ni < 4; ++ni) {
      const int px = wc * 64 + ni * 16 + l15;
      f32x4 a = acc[mi][ni];
      float t0 = a[0] + bv0; t0 = t0 > 0.f ? t0 : 0.f;
      float t1 = a[1] + bv1; t1 = t1 > 0.f ? t1 : 0.f;
      float t2 = a[2] + bv2; t2 = t2 > 0.f ? t2 : 0.f;
      float t3 = a[3] + bv3; t3 = t3 > 0.f ? t3 : 0.f;
      bf16x4 v = {(bf16)t0, (bf16)t1, (bf16)t2, (bf16)t3};
      *(bf16x4*)(mid + (long)(h * 128 + px) * 512 + oc) = v;
    }
  }
}

// ---------------- head: barrier-free K-split GEMM + anchor decode ----------
__global__ __launch_bounds__(256) void head_gemm(
    const bf16* __restrict__ w2p, const bf16* __restrict__ mid,
    const float* __restrict__ loc_b, const float* __restrict__ score_b,
    float* __restrict__ out) {
  __shared__ f32x4 red[3][64][5];
  const int tid  = threadIdx.x;
  const int wave = tid >> 6;
  const int lane = tid & 63;
  const int quad = lane >> 4;
  const int l15  = lane & 15;
  const int px0  = blockIdx.x * 16;
  const bf16* mB = mid + (long)px0 * 512;

  f32x4 acc[5];
#pragma unroll
  for (int i = 0; i < 5; ++i) acc[i] = (f32x4){0.f, 0.f, 0.f, 0.f};

#pragma unroll
  for (int st = 0; st < 4; ++st) {
    const int k0 = wave * 128 + st * 32;
    bf16x8 bfr = *(const bf16x8*)(mB + (long)l15 * 512 + k0 + quad * 8);
#pragma unroll
    for (int mi = 0; mi < 5; ++mi) {
      bf16x8 af = *(const bf16x8*)(w2p + (long)(mi * 16 + l15) * 512 + k0 + quad * 8);
      acc[mi] = __builtin_amdgcn_mfma_f32_16x16x32_bf16(af, bfr, acc[mi], 0, 0, 0);
    }
  }

  if (wave > 0) {
#pragma unroll
    for (int mi = 0; mi < 5; ++mi) red[wave - 1][lane][mi] = acc[mi];
  }
  __syncthreads();
  if (wave != 0) return;
#pragma unroll
  for (int w = 0; w < 3; ++w)
#pragma unroll
    for (int mi = 0; mi < 5; ++mi) acc[mi] += red[w][lane][mi];

  const int p    = px0 + l15;
  const int hh   = p >> 7;
  const int wcol = p & 127;
  const float cx = 16.f * (float)hh;
  const float cy = 16.f * (float)wcol;
  const float s0 = quad == 0 ? 45.f : quad == 1 ? 91.f : quad == 2 ? 181.f : 362.f;
  const float s1 = quad == 0 ? 32.f : quad == 1 ? 64.f : quad == 2 ? 128.f : 256.f;
  const float s2 = quad == 0 ? 23.f : quad == 1 ? 45.f : quad == 2 ? 91.f : 181.f;
  const float aw[3] = {s0, s1, s2};
  const float ah[3] = {s2, s1, s0};
#pragma unroll
  for (int mi = 0; mi < 5; ++mi) {
#pragma unroll
    for (int r = 0; r < 4; ++r) {
      const int oc2 = mi * 16 + quad * 4 + r;
      float v = acc[mi][r];
      if (mi < 3) {
        v += loc_b[oc2];
        out[p * 48 + oc2] = v;
        float roi;
        if (r == 0)      roi = v * aw[mi] + cx;
        else if (r == 1) roi = v * ah[mi] + cy;
        else if (r == 2) roi = __expf(v) * aw[mi];
        else             roi = __expf(v) * ah[mi];
        out[OUT_ROI + p * 48 + oc2] = roi;
      } else {
        const int sc = oc2 - 48;
        if (sc < 24) {
          v += score_b[sc];
          out[OUT_CLS + p * 24 + sc] = v;
        }
      }
    }
  }
}

// ---------------------------------------------------------------------------
extern "C" void kernel_launch(void* const* d_in, const int* in_sizes, int n_in,
                              void* d_out, int out_size, void* d_ws, size_t ws_size,
                              hipStream_t stream) {
  (void)in_sizes; (void)n_in; (void)out_size; (void)ws_size;
  const float* x       = (const float*)d_in[0];
  const float* conv1_w = (const float*)d_in[1];
  const float* conv1_b = (const float*)d_in[2];
  const float* score_w = (const float*)d_in[3];
  const float* score_b = (const float*)d_in[4];
  const float* loc_w   = (const float*)d_in[5];
  const float* loc_b   = (const float*)d_in[6];
  char* ws = (char*)d_ws;
  bf16* xh  = (bf16*)(ws + WS_XH);
  bf16* w1t = (bf16*)(ws + WS_W1T);
  bf16* w2p = (bf16*)(ws + WS_W2P);
  bf16* mid = (bf16*)(ws + WS_MID);
  float* out = (float*)d_out;

  hipLaunchKernelGGL(prep_misc,   dim3(1316), dim3(256), 0, stream,
                     (int4*)xh, conv1_w, w1t, loc_w, score_w, w2p);
  hipLaunchKernelGGL(transpose_x, dim3(2048), dim3(256), 0, stream, x, xh);
  hipLaunchKernelGGL(conv1_gemm,  dim3(512),  dim3(256), 0, stream, w1t, xh, conv1_b, mid);
  hipLaunchKernelGGL(head_gemm,   dim3(1024), dim3(256), 0, stream, w2p, mid, loc_b, score_b, out);
}